// Round 6
// baseline (170.258 us; speedup 1.0000x reference)
//
#include <hip/hip_runtime.h>
#include <hip/hip_bf16.h>
#include <stdint.h>

typedef __attribute__((ext_vector_type(8))) short bf16x8;  // 8 bf16 (4 VGPRs)
typedef __attribute__((ext_vector_type(4))) float f32x4;   // 4 f32 acc

#define RD 1024
#define LD 112
#define SCALE_C 2.8853900817779268f   // 2/ln2: tanh(z) = 1 - 2/(1+2^(C*z))
#define CHK 64                        // k per LDS chunk in fence_out
#define NCHK (RD/CHK)                 // 16 chunks
// flat LDS chunk buffer layout (bytes): Pt2 14 KB | E 4 KB | F 2 KB = 20 KB
#define OFF_E 14336
#define OFF_F 18432
// fence_pre block ranges
#define NB_Y   400                    // 400 blocks x 4 waves = 1600 y-tiles
#define NB_PT  448                    // 448 blocks x 256 = 112*1024 Pt2 elems

static __device__ __forceinline__ unsigned pkbf(float lo, float hi){
  return __builtin_amdgcn_perm(__builtin_bit_cast(unsigned, hi),
                               __builtin_bit_cast(unsigned, lo), 0x07060302u);
}
static __device__ __forceinline__ float exp2_f(float t){
#if __has_builtin(__builtin_amdgcn_exp2f)
  return __builtin_amdgcn_exp2f(t);
#else
  return exp2f(t);
#endif
}
static __device__ __forceinline__ float rcp_f(float t){
#if __has_builtin(__builtin_amdgcn_rcpf)
  return __builtin_amdgcn_rcpf(t);
#else
  return 1.0f / t;
#endif
}
static __device__ __forceinline__ short f2bf_rn(float f){
  unsigned u = __builtin_bit_cast(unsigned, f);
  return (short)((u + 0x7fffu + ((u >> 16) & 1u)) >> 16);
}
typedef const __attribute__((address_space(1))) unsigned int* gas1;
typedef __attribute__((address_space(3))) unsigned int* las3;
static __device__ __forceinline__ void g2lds16(const void* g, void* l){
  __builtin_amdgcn_global_load_lds((gas1)g, (las3)l, 16, 0, 0);
}

// ---- fence_pre: [blk<400] y=fp*W^T tiles, f32 inputs packed in-register,
//      epilogue E=2^(C(y+b)), F=2^(-Cy); [400..848) Pt2 transpose; [848..960) SB ----
__global__ __launch_bounds__(256, 2)
void fence_pre(const float* __restrict__ x, const float* __restrict__ W,
               const float* __restrict__ b, const float* __restrict__ P,
               const float* __restrict__ ob, short* __restrict__ Pt2,
               float* __restrict__ SB, float* __restrict__ E,
               float* __restrict__ F, int ntok){
  __shared__ float red[256];
  int blk = blockIdx.x, t = threadIdx.x;
  int nn = ntok - 1;
  if (blk < NB_Y){
    int wid  = blk*4 + (t >> 6);
    int lane = t & 63;
    int mt = wid >> 6;          // 0..24
    int ng = wid & 63;          // 0..63
    int lm = lane & 15, rq = lane >> 4;
    int arow = mt*16 + lm;
    unsigned zmask = (arow < nn) ? 0xFFFFFFFFu : 0u;   // pad rows (>=nn) -> 0
    int ar = (arow < nn) ? arow : 0;
    const float* xa = x + (size_t)ar*RD;          // fp[t][d<512]  =  x[t][d]
    const float* xb = x + (size_t)(ar+1)*RD;      // fp[t][d>=512] = -x[t+1][d]
    const float* wp = W + (size_t)(ng*16 + lm)*RD;
    f32x4 acc = {};
    #pragma unroll 4
    for (int kb = 0; kb < 32; ++kb){
      int d0 = kb*32 + rq*8;
      bool side = (d0 >= 512);
      const float* ap = (side ? xb : xa) + d0;
      unsigned sm = side ? 0x80008000u : 0u;      // negate both packed bf16
      float4 a0 = *(const float4*)ap;
      float4 a1 = *(const float4*)(ap + 4);
      float4 w0 = *(const float4*)(wp + d0);
      float4 w1 = *(const float4*)(wp + d0 + 4);
      union { unsigned u4[4]; bf16x8 v; } af, wf;
      af.u4[0] = (pkbf(a0.x, a0.y) ^ sm) & zmask;
      af.u4[1] = (pkbf(a0.z, a0.w) ^ sm) & zmask;
      af.u4[2] = (pkbf(a1.x, a1.y) ^ sm) & zmask;
      af.u4[3] = (pkbf(a1.z, a1.w) ^ sm) & zmask;
      wf.u4[0] = pkbf(w0.x, w0.y); wf.u4[1] = pkbf(w0.z, w0.w);
      wf.u4[2] = pkbf(w1.x, w1.y); wf.u4[3] = pkbf(w1.z, w1.w);
      acc = __builtin_amdgcn_mfma_f32_16x16x32_bf16(af.v, wf.v, acc, 0, 0, 0);
    }
    int r = ng*16 + lm;
    float bv = b[r];
    #pragma unroll
    for (int reg = 0; reg < 4; ++reg){
      int tt = mt*16 + rq*4 + reg;
      if (tt < ntok){
        float y = acc[reg];
        E[(size_t)tt*RD + r] = exp2_f(SCALE_C * (y + bv));
        F[(size_t)tt*RD + r] = exp2_f(-SCALE_C * y);
      }
    }
  } else if (blk < NB_Y + NB_PT){
    int p = (blk - NB_Y)*256 + t;      // < LD*RD
    int l = p >> 10, r = p & (RD - 1);
    Pt2[p] = f2bf_rn(-2.0f * P[r*LD + l]);
  } else {
    int l = blk - (NB_Y + NB_PT);      // 0..LD-1
    float s = 0.0f;
    for (int r = t; r < RD; r += 256) s += P[r*LD + l];
    red[t] = s; __syncthreads();
    for (int st = 128; st > 0; st >>= 1){
      if (t < st) red[t] += red[t + st];
      __syncthreads();
    }
    if (t == 0) SB[l] = red[0] + ob[l];
  }
}

// ---- fence_out: out[i,j,l] = SB[l] - 2*sum_r sigma*P[r,l], sigma=1/(1+E_j F_i).
//      Block = 8i x 16j, 4 waves x 2 i-rows. Pt2/E/F staged per 64-k chunk via
//      global_load_lds (double-buffered 2x20 KB). E chunk XOR-swizzled at float4
//      granularity (bank-conflict-free, verified R5). BYTE-IDENTICAL to R5. ----
__global__ __launch_bounds__(256, 4)
void fence_out(const float* __restrict__ E, const float* __restrict__ F,
               const short* __restrict__ Pt2, const float* __restrict__ SB,
               float* __restrict__ out, int nn, int njt){
  __shared__ __align__(16) char sbuf[2][20480];
  int wave = threadIdx.x >> 6, lane = threadIdx.x & 63;
  int lm = lane & 15, rq = lane >> 4;
  int it = blockIdx.x / njt, jt = blockIdx.x - it*njt;
  int ibase = it*8, jbase = jt*16;

  const char* gp[5]; int lof[5]; int stp[5];
  #pragma unroll
  for (int s = 0; s < 5; ++s){
    int q = wave + s*4;
    if (q < 14){
      int kb = q / 7, g = q - kb*7;
      gp[s]  = (const char*)(Pt2 + (size_t)(g*16 + lm)*RD + kb*32 + rq*8);
      stp[s] = CHK*2;
      lof[s] = q*1024;
    } else if (q < 18){
      int ee = q - 14;
      int row = ee*4 + rq;
      int jr = jbase + row; if (jr > nn - 1) jr = nn - 1;
      int cb = lm ^ row;
      gp[s]  = (const char*)(E + (size_t)jr*RD + cb*4);
      stp[s] = CHK*4;
      lof[s] = OFF_E + ee*1024;
    } else {
      int ff = q - 18;
      int row = ff*4 + rq;
      int ir = ibase + row; if (ir > nn - 1) ir = nn - 1;
      gp[s]  = (const char*)(F + (size_t)ir*RD + lm*4);
      stp[s] = CHK*4;
      lof[s] = OFF_F + ff*1024;
    }
  }
  auto stage = [&](int c, int bi){
    #pragma unroll
    for (int s = 0; s < 5; ++s)
      g2lds16(gp[s] + (size_t)c*stp[s], &sbuf[bi][lof[s]]);
  };

  stage(0, 0);

  f32x4 acc[2][7];
  #pragma unroll
  for (int nt = 0; nt < 7; ++nt){
    float sv = SB[nt*16 + lm];
    acc[0][nt] = (f32x4){sv, sv, sv, sv};
    acc[1][nt] = (f32x4){sv, sv, sv, sv};
  }
  __syncthreads();

  for (int c = 0; c < NCHK; ++c){
    int bi = c & 1;
    if (c + 1 < NCHK) stage(c + 1, bi ^ 1);
    const short* pb = (const short*)&sbuf[bi][0];
    const float* eb = (const float*)&sbuf[bi][OFF_E];
    const float* fb = (const float*)&sbuf[bi][OFF_F];
    #pragma unroll
    for (int kb = 0; kb < 2; ++kb){
      int ko = kb*32 + rq*8;
      int cb0 = kb*8 + rq*2;
      float4 e0 = *(const float4*)(eb + lm*64 + ((cb0 ^ lm) * 4));
      float4 e1 = *(const float4*)(eb + lm*64 + (((cb0 + 1) ^ lm) * 4));
      bf16x8 af[2];
      #pragma unroll
      for (int u = 0; u < 2; ++u){
        const float* fr = fb + (wave*2 + u)*64 + ko;
        float4 f0 = *(const float4*)fr;
        float4 f1 = *(const float4*)(fr + 4);
        float s0 = rcp_f(fmaf(e0.x, f0.x, 1.0f));
        float s1 = rcp_f(fmaf(e0.y, f0.y, 1.0f));
        float s2 = rcp_f(fmaf(e0.z, f0.z, 1.0f));
        float s3 = rcp_f(fmaf(e0.w, f0.w, 1.0f));
        float s4 = rcp_f(fmaf(e1.x, f1.x, 1.0f));
        float s5 = rcp_f(fmaf(e1.y, f1.y, 1.0f));
        float s6 = rcp_f(fmaf(e1.z, f1.z, 1.0f));
        float s7 = rcp_f(fmaf(e1.w, f1.w, 1.0f));
        union { unsigned u4[4]; bf16x8 v; } a;
        a.u4[0] = pkbf(s0, s1); a.u4[1] = pkbf(s2, s3);
        a.u4[2] = pkbf(s4, s5); a.u4[3] = pkbf(s6, s7);
        af[u] = a.v;
      }
      #pragma unroll
      for (int nt = 0; nt < 7; ++nt){
        bf16x8 pf = *(const bf16x8*)(pb + (kb*7 + nt)*512 + lane*8);
        acc[0][nt] = __builtin_amdgcn_mfma_f32_16x16x32_bf16(af[0], pf, acc[0][nt], 0, 0, 0);
        acc[1][nt] = __builtin_amdgcn_mfma_f32_16x16x32_bf16(af[1], pf, acc[1][nt], 0, 0, 0);
      }
    }
    __syncthreads();
  }

  #pragma unroll
  for (int u = 0; u < 2; ++u){
    int i = ibase + wave*2 + u;
    if (i >= nn) continue;
    size_t dbase = (size_t)i * nn * LD;
    #pragma unroll
    for (int reg = 0; reg < 4; ++reg){
      int j = jbase + rq*4 + reg;
      if (j >= nn) continue;
      float* op = out + dbase + (size_t)j*LD + lm;
      #pragma unroll
      for (int nt = 0; nt < 7; ++nt) op[nt*16] = acc[u][nt][reg];
    }
  }
}

extern "C" void kernel_launch(void* const* d_in, const int* in_sizes, int n_in,
                              void* d_out, int out_size, void* d_ws, size_t ws_size,
                              hipStream_t stream){
  const float* x  = (const float*)d_in[0];
  const float* W  = (const float*)d_in[1];
  const float* b  = (const float*)d_in[2];
  const float* P  = (const float*)d_in[3];
  const float* ob = (const float*)d_in[4];
  int ntok = in_sizes[0] / RD;   // 400
  int nn = ntok - 1;             // 399

  char* ws = (char*)d_ws;
  size_t o_Pt2 = 0;
  size_t o_E   = o_Pt2 + (size_t)LD*RD*2;
  size_t o_F   = o_E   + (size_t)ntok*RD*4;
  size_t o_SB  = o_F   + (size_t)ntok*RD*4;
  short* Pt2 = (short*)(ws + o_Pt2);
  float* E   = (float*)(ws + o_E);
  float* F   = (float*)(ws + o_F);
  float* SB  = (float*)(ws + o_SB);

  fence_pre<<<NB_Y + NB_PT + LD, 256, 0, stream>>>(x, W, b, P, ob, Pt2, SB, E, F, ntok);

  int njt = (nn + 15) / 16;            // 25
  int nit = (nn + 7) / 8;              // 50
  fence_out<<<nit*njt, 256, 0, stream>>>(E, F, Pt2, SB, (float*)d_out, nn, njt);
}